// Round 2
// baseline (679.456 us; speedup 1.0000x reference)
//
#include <hip/hip_runtime.h>

#define NN 50000
#define NE 800000
#define NG 64
#define HID 64
#define NEG 0.2f

// ---------------- K1: h = x @ W ; a_s = h.att_src ; a_d = h.att_dst --------
// block 256 = 4 waves; each wave computes one row of h; lane = output channel
__global__ __launch_bounds__(256)
void k_xw(const float* __restrict__ x, const float* __restrict__ W,
          const float* __restrict__ att_s, const float* __restrict__ att_d,
          float* __restrict__ h, float* __restrict__ as_, float* __restrict__ ad_) {
    __shared__ float sW[64][64];   // W[k][c]; lane-varying c => conflict-free
    int t = threadIdx.x;
    for (int i = t; i < 4096; i += 256) sW[i >> 6][i & 63] = W[i];
    __syncthreads();
    int wave = t >> 6, lane = t & 63;
    int row = blockIdx.x * 4 + wave;
    if (row >= NN) return;
    float xk = x[row * 64 + lane];         // coalesced; then broadcast via shuffle
    float acc = 0.f;
    #pragma unroll
    for (int k = 0; k < 64; ++k)
        acc += __shfl(xk, k, 64) * sW[k][lane];
    h[row * 64 + lane] = acc;
    // wave-reduce for a_s, a_d
    float ps = acc * att_s[lane];
    float pd = acc * att_d[lane];
    #pragma unroll
    for (int m = 32; m >= 1; m >>= 1) {
        ps += __shfl_xor(ps, m, 64);
        pd += __shfl_xor(pd, m, 64);
    }
    if (lane == 0) { as_[row] = ps; ad_[row] = pd; }
}

// ---------------- K2: edge scatter (one wave per edge) ---------------------
// out_u[d][c] += h[s][c] * exp(e);  denom[d] += exp(e)
// max-subtraction skipped: |e| <= ~3 here, exp cannot overflow; softmax is
// shift-invariant so the result matches the reference to rounding.
__global__ __launch_bounds__(256)
void k_edge(const int* __restrict__ src, const int* __restrict__ dst,
            const float* __restrict__ h,
            const float* __restrict__ as_, const float* __restrict__ ad_,
            float* __restrict__ out_u, float* __restrict__ denom) {
    int t = threadIdx.x;
    int wave = t >> 6, lane = t & 63;
    int e = blockIdx.x * 4 + wave;
    if (e >= NE + NN) return;
    int s, d;
    if (e < NE) { s = src[e]; d = dst[e]; }
    else        { s = e - NE; d = s; }          // self-loop
    float av = as_[s] + ad_[d];
    float lr = av >= 0.f ? av : NEG * av;       // leaky_relu
    float ex = __expf(lr);
    float hv = h[s * 64 + lane] * ex;           // coalesced 256B gather
    atomicAdd(&out_u[d * 64 + lane], hv);
    if (lane == 0) atomicAdd(&denom[d], ex);
}

// ---------------- K3: normalize + ReLU + segment-mean-pool (sum part) ------
__global__ __launch_bounds__(256)
void k_node(const float* __restrict__ out_u, const float* __restrict__ denom,
            const float* __restrict__ bias, const int* __restrict__ batch,
            float* __restrict__ pooled, float* __restrict__ cnt) {
    int t = threadIdx.x;
    int wave = t >> 6, lane = t & 63;
    int n = blockIdx.x * 4 + wave;
    if (n >= NN) return;
    float g = out_u[n * 64 + lane] / denom[n] + bias[lane];
    g = fmaxf(g, 0.f);
    int gr = batch[n];
    atomicAdd(&pooled[gr * 64 + lane], g);
    if (lane == 0) atomicAdd(&cnt[gr], 1.0f);
}

// ---------------- K4: mean + MLP + sigmoid (single block) ------------------
__global__ __launch_bounds__(256)
void k_final(const float* __restrict__ pooled, const float* __restrict__ cnt,
             const float* __restrict__ w1, const float* __restrict__ b1,
             const float* __restrict__ w2, const float* __restrict__ b2,
             float* __restrict__ out) {
    __shared__ float sp[64][65];
    __shared__ float sz[64][65];
    int t = threadIdx.x;
    for (int i = t; i < 4096; i += 256) {
        int g = i >> 6, c = i & 63;
        sp[g][c] = pooled[i] / fmaxf(cnt[g], 1.0f);
    }
    __syncthreads();
    for (int i = t; i < 4096; i += 256) {
        int g = i >> 6, c = i & 63;
        float acc = b1[c];
        #pragma unroll
        for (int k = 0; k < 64; ++k) acc += sp[g][k] * w1[k * 64 + c];
        sz[g][c] = fmaxf(acc, 0.f);
    }
    __syncthreads();
    if (t < 64) {
        float acc = b2[0];
        #pragma unroll
        for (int c = 0; c < 64; ++c) acc += sz[t][c] * w2[c];
        out[t] = 1.f / (1.f + __expf(-acc));
    }
}

extern "C" void kernel_launch(void* const* d_in, const int* in_sizes, int n_in,
                              void* d_out, int out_size, void* d_ws, size_t ws_size,
                              hipStream_t stream) {
    const float* x     = (const float*)d_in[0];
    const int*   ei    = (const int*)d_in[1];   // [2, NE] flat: src row then dst row
    const int*   batch = (const int*)d_in[2];
    const float* W     = (const float*)d_in[3];
    const float* att_s = (const float*)d_in[4];
    const float* att_d = (const float*)d_in[5];
    const float* bias  = (const float*)d_in[6];
    const float* w1    = (const float*)d_in[7];
    const float* b1    = (const float*)d_in[8];
    const float* w2    = (const float*)d_in[9];
    const float* b2    = (const float*)d_in[10];
    float* out = (float*)d_out;

    // workspace layout (floats)
    float* h      = (float*)d_ws;             // NN*64
    float* as_    = h + (size_t)NN * HID;     // NN
    float* ad_    = as_ + NN;                 // NN
    float* out_u  = ad_ + NN;                 // NN*64   (zeroed region starts here)
    float* denom  = out_u + (size_t)NN * HID; // NN
    float* pooled = denom + NN;               // NG*64
    float* cntp   = pooled + NG * HID;        // NG

    size_t zbytes = ((size_t)NN * HID + NN + NG * HID + NG) * sizeof(float);
    hipMemsetAsync(out_u, 0, zbytes, stream);

    k_xw<<<(NN + 3) / 4, 256, 0, stream>>>(x, W, att_s, att_d, h, as_, ad_);

    int M = NE + NN;
    k_edge<<<(M + 3) / 4, 256, 0, stream>>>(ei, ei + NE, h, as_, ad_, out_u, denom);

    k_node<<<(NN + 3) / 4, 256, 0, stream>>>(out_u, denom, bias, batch, pooled, cntp);

    k_final<<<1, 256, 0, stream>>>(pooled, cntp, w1, b1, w2, b2, out);
}

// Round 3
// 335.871 us; speedup vs baseline: 2.0230x; 2.0230x over previous
//
#include <hip/hip_runtime.h>

#define NN 50000
#define NE 800000
#define NG 64
#define HID 64
#define NEG 0.2f
#define NPW 64   // nodes per wave in k_node

// ---------------- K1: h = x @ W ; a_s = h.att_src ; a_d = h.att_dst --------
__global__ __launch_bounds__(256)
void k_xw(const float* __restrict__ x, const float* __restrict__ W,
          const float* __restrict__ att_s, const float* __restrict__ att_d,
          float* __restrict__ h, float* __restrict__ as_, float* __restrict__ ad_) {
    __shared__ float sW[64][64];   // W[k][c]; lane-varying c => conflict-free
    int t = threadIdx.x;
    for (int i = t; i < 4096; i += 256) sW[i >> 6][i & 63] = W[i];
    __syncthreads();
    int wave = t >> 6, lane = t & 63;
    int row = blockIdx.x * 4 + wave;
    if (row >= NN) return;
    float xk = x[row * 64 + lane];         // coalesced; then broadcast via shuffle
    float acc = 0.f;
    #pragma unroll
    for (int k = 0; k < 64; ++k)
        acc += __shfl(xk, k, 64) * sW[k][lane];
    h[row * 64 + lane] = acc;
    float ps = acc * att_s[lane];
    float pd = acc * att_d[lane];
    #pragma unroll
    for (int m = 32; m >= 1; m >>= 1) {
        ps += __shfl_xor(ps, m, 64);
        pd += __shfl_xor(pd, m, 64);
    }
    if (lane == 0) { as_[row] = ps; ad_[row] = pd; }
}

// ---------------- K2: edge scatter (one wave per edge) ---------------------
// out_u[d][c] += h[s][c] * exp(e);  denom[d] += exp(e)
// max-subtraction skipped: |e| <= ~3 here, exp cannot overflow; softmax is
// shift-invariant so the result matches the reference to rounding.
__global__ __launch_bounds__(256)
void k_edge(const int* __restrict__ src, const int* __restrict__ dst,
            const float* __restrict__ h,
            const float* __restrict__ as_, const float* __restrict__ ad_,
            float* __restrict__ out_u, float* __restrict__ denom) {
    int t = threadIdx.x;
    int wave = t >> 6, lane = t & 63;
    int e = blockIdx.x * 4 + wave;
    if (e >= NE + NN) return;
    int s, d;
    if (e < NE) { s = src[e]; d = dst[e]; }
    else        { s = e - NE; d = s; }          // self-loop
    float av = as_[s] + ad_[d];
    float lr = av >= 0.f ? av : NEG * av;       // leaky_relu
    float ex = __expf(lr);
    float hv = h[s * 64 + lane] * ex;           // coalesced 256B gather
    atomicAdd(&out_u[d * 64 + lane], hv);
    if (lane == 0) atomicAdd(&denom[d], ex);
}

// ---------------- K3: normalize + ReLU + pooled partial sums ---------------
// batch is SORTED: run-length accumulate in registers, flush one atomic per
// graph-boundary per wave. 3.2M atomics -> ~100k.
__global__ __launch_bounds__(256)
void k_node(const float* __restrict__ out_u, const float* __restrict__ denom,
            const float* __restrict__ bias, const int* __restrict__ batch,
            float* __restrict__ pooled, float* __restrict__ cnt) {
    int t = threadIdx.x;
    int wave = t >> 6, lane = t & 63;
    int n0 = (blockIdx.x * 4 + wave) * NPW;
    if (n0 >= NN) return;
    int n1 = n0 + NPW; if (n1 > NN) n1 = NN;
    float b = bias[lane];
    float acc = 0.f, c = 0.f;
    int cur = batch[n0];
    for (int n = n0; n < n1; ++n) {
        int gr = batch[n];                     // wave-uniform scalar load
        if (gr != cur) {
            atomicAdd(&pooled[cur * 64 + lane], acc);
            if (lane == 0) atomicAdd(&cnt[cur], c);
            acc = 0.f; c = 0.f; cur = gr;
        }
        float g = fmaxf(out_u[n * 64 + lane] / denom[n] + b, 0.f);
        acc += g; c += 1.f;
    }
    atomicAdd(&pooled[cur * 64 + lane], acc);
    if (lane == 0) atomicAdd(&cnt[cur], c);
}

// ---------------- K4: mean + MLP + sigmoid (single block) ------------------
__global__ __launch_bounds__(256)
void k_final(const float* __restrict__ pooled, const float* __restrict__ cnt,
             const float* __restrict__ w1, const float* __restrict__ b1,
             const float* __restrict__ w2, const float* __restrict__ b2,
             float* __restrict__ out) {
    __shared__ float sp[64][65];
    __shared__ float sz[64][65];
    int t = threadIdx.x;
    for (int i = t; i < 4096; i += 256) {
        int g = i >> 6, c = i & 63;
        sp[g][c] = pooled[i] / fmaxf(cnt[g], 1.0f);
    }
    __syncthreads();
    for (int i = t; i < 4096; i += 256) {
        int g = i >> 6, c = i & 63;
        float acc = b1[c];
        #pragma unroll
        for (int k = 0; k < 64; ++k) acc += sp[g][k] * w1[k * 64 + c];
        sz[g][c] = fmaxf(acc, 0.f);
    }
    __syncthreads();
    if (t < 64) {
        float acc = b2[0];
        #pragma unroll
        for (int c = 0; c < 64; ++c) acc += sz[t][c] * w2[c];
        out[t] = 1.f / (1.f + __expf(-acc));
    }
}

extern "C" void kernel_launch(void* const* d_in, const int* in_sizes, int n_in,
                              void* d_out, int out_size, void* d_ws, size_t ws_size,
                              hipStream_t stream) {
    const float* x     = (const float*)d_in[0];
    const int*   ei    = (const int*)d_in[1];   // [2, NE] flat: src row then dst row
    const int*   batch = (const int*)d_in[2];
    const float* W     = (const float*)d_in[3];
    const float* att_s = (const float*)d_in[4];
    const float* att_d = (const float*)d_in[5];
    const float* bias  = (const float*)d_in[6];
    const float* w1    = (const float*)d_in[7];
    const float* b1    = (const float*)d_in[8];
    const float* w2    = (const float*)d_in[9];
    const float* b2    = (const float*)d_in[10];
    float* out = (float*)d_out;

    // workspace layout (floats)
    float* h      = (float*)d_ws;             // NN*64
    float* as_    = h + (size_t)NN * HID;     // NN
    float* ad_    = as_ + NN;                 // NN
    float* out_u  = ad_ + NN;                 // NN*64   (zeroed region starts here)
    float* denom  = out_u + (size_t)NN * HID; // NN
    float* pooled = denom + NN;               // NG*64
    float* cntp   = pooled + NG * HID;        // NG

    size_t zbytes = ((size_t)NN * HID + NN + NG * HID + NG) * sizeof(float);
    hipMemsetAsync(out_u, 0, zbytes, stream);

    k_xw<<<(NN + 3) / 4, 256, 0, stream>>>(x, W, att_s, att_d, h, as_, ad_);

    int M = NE + NN;
    k_edge<<<(M + 3) / 4, 256, 0, stream>>>(ei, ei + NE, h, as_, ad_, out_u, denom);

    k_node<<<(NN / (4 * NPW)) + 1, 256, 0, stream>>>(out_u, denom, bias, batch, pooled, cntp);

    k_final<<<1, 256, 0, stream>>>(pooled, cntp, w1, b1, w2, b2, out);
}

// Round 4
// 324.508 us; speedup vs baseline: 2.0938x; 1.0350x over previous
//
#include <hip/hip_runtime.h>

#define NN 50000
#define NE 800000
#define NG 64
#define HID 64
#define NEG 0.2f
#define NPW 64   // nodes per wave in k_node

// ---------------- K1: h = x @ W ; a_s = h.att_src ; a_d = h.att_dst --------
__global__ __launch_bounds__(256)
void k_xw(const float* __restrict__ x, const float* __restrict__ W,
          const float* __restrict__ att_s, const float* __restrict__ att_d,
          float* __restrict__ h, float* __restrict__ as_, float* __restrict__ ad_) {
    __shared__ float sW[64][64];   // W[k][c]; lane-varying c => conflict-free
    int t = threadIdx.x;
    for (int i = t; i < 4096; i += 256) sW[i >> 6][i & 63] = W[i];
    __syncthreads();
    int wave = t >> 6, lane = t & 63;
    int row = blockIdx.x * 4 + wave;
    if (row >= NN) return;
    float xk = x[row * 64 + lane];         // coalesced; then broadcast
    float acc = 0.f;
    #pragma unroll
    for (int k = 0; k < 64; ++k)
        acc += __shfl(xk, k, 64) * sW[k][lane];
    h[row * 64 + lane] = acc;
    float ps = acc * att_s[lane];
    float pd = acc * att_d[lane];
    #pragma unroll
    for (int m = 32; m >= 1; m >>= 1) {
        ps += __shfl_xor(ps, m, 64);
        pd += __shfl_xor(pd, m, 64);
    }
    if (lane == 0) { as_[row] = ps; ad_[row] = pd; }
}

// ---------------- CSR build: degree count --------------------------------
__global__ __launch_bounds__(256)
void k_deg(const int* __restrict__ dst, int* __restrict__ deg) {
    int e = blockIdx.x * 256 + threadIdx.x;
    if (e < NE) atomicAdd(&deg[dst[e]], 1);
}

// ---------------- CSR build: prefix scan (single block) -------------------
// cursor[i] = exclusive prefix sum of deg (start offset of node i)
__global__ __launch_bounds__(256)
void k_scan(const int* __restrict__ deg, int* __restrict__ cursor) {
    __shared__ int part[256];
    int t = threadIdx.x;
    const int chunk = (NN + 255) / 256;           // 196
    int c0 = t * chunk, c1 = c0 + chunk; if (c1 > NN) c1 = NN;
    int s = 0;
    for (int i = c0; i < c1; ++i) s += deg[i];
    part[t] = s;
    __syncthreads();
    // Hillis-Steele inclusive scan over 256 partials
    for (int off = 1; off < 256; off <<= 1) {
        int v = (t >= off) ? part[t - off] : 0;
        __syncthreads();
        part[t] += v;
        __syncthreads();
    }
    int base = (t == 0) ? 0 : part[t - 1];
    for (int i = c0; i < c1; ++i) { cursor[i] = base; base += deg[i]; }
}

// ---------------- CSR build: fill (cursor advances to end offset) ---------
__global__ __launch_bounds__(256)
void k_fill(const int* __restrict__ src, const int* __restrict__ dst,
            int* __restrict__ cursor, int* __restrict__ csr) {
    int e = blockIdx.x * 256 + threadIdx.x;
    if (e < NE) {
        int p = atomicAdd(&cursor[dst[e]], 1);
        csr[p] = src[e];
    }
}

// ---------------- K2': gather per dst node (no atomics) -------------------
// g[d] = relu( (sum_s h[s]*exp(lrelu(as[s]+ad[d]))) / (sum exp) + bias )
// self-loop folded in analytically. After k_fill, cursor[d] = end offset.
__global__ __launch_bounds__(256)
void k_gather(const int* __restrict__ csr, const int* __restrict__ cursor,
              const int* __restrict__ deg, const float* __restrict__ h,
              const float* __restrict__ as_, const float* __restrict__ ad_,
              const float* __restrict__ bias, float* __restrict__ g) {
    int t = threadIdx.x;
    int wave = t >> 6, lane = t & 63;
    int d = blockIdx.x * 4 + wave;
    if (d >= NN) return;
    int cend = cursor[d];
    int nd   = deg[d];
    int cbeg = cend - nd;
    float adv = ad_[d];
    // self loop (s = d)
    float e0 = as_[d] + adv;
    e0 = e0 >= 0.f ? e0 : NEG * e0;
    float ex0 = __expf(e0);
    float den = ex0;
    float acc = h[(size_t)d * 64 + lane] * ex0;
    #pragma unroll 4
    for (int c = cbeg; c < cend; ++c) {
        int s = csr[c];                           // wave-uniform (broadcast)
        float av = as_[s] + adv;
        av = av >= 0.f ? av : NEG * av;
        float ex = __expf(av);
        den += ex;
        acc += h[(size_t)s * 64 + lane] * ex;     // 256B coalesced gather
    }
    g[(size_t)d * 64 + lane] = fmaxf(acc / den + bias[lane], 0.f);
}

// ---------------- K3: pooled partial sums (batch sorted, run-length) ------
__global__ __launch_bounds__(256)
void k_node(const float* __restrict__ g, const int* __restrict__ batch,
            float* __restrict__ pooled, float* __restrict__ cnt) {
    int t = threadIdx.x;
    int wave = t >> 6, lane = t & 63;
    int n0 = (blockIdx.x * 4 + wave) * NPW;
    if (n0 >= NN) return;
    int n1 = n0 + NPW; if (n1 > NN) n1 = NN;
    float acc = 0.f, c = 0.f;
    int cur = batch[n0];
    for (int n = n0; n < n1; ++n) {
        int gr = batch[n];
        if (gr != cur) {
            atomicAdd(&pooled[cur * 64 + lane], acc);
            if (lane == 0) atomicAdd(&cnt[cur], c);
            acc = 0.f; c = 0.f; cur = gr;
        }
        acc += g[(size_t)n * 64 + lane];
        c += 1.f;
    }
    atomicAdd(&pooled[cur * 64 + lane], acc);
    if (lane == 0) atomicAdd(&cnt[cur], c);
}

// ---------------- K4: mean + MLP + sigmoid (single block) ------------------
__global__ __launch_bounds__(256)
void k_final(const float* __restrict__ pooled, const float* __restrict__ cnt,
             const float* __restrict__ w1, const float* __restrict__ b1,
             const float* __restrict__ w2, const float* __restrict__ b2,
             float* __restrict__ out) {
    __shared__ float sp[64][65];
    __shared__ float sz[64][65];
    int t = threadIdx.x;
    for (int i = t; i < 4096; i += 256) {
        int g = i >> 6, c = i & 63;
        sp[g][c] = pooled[i] / fmaxf(cnt[g], 1.0f);
    }
    __syncthreads();
    for (int i = t; i < 4096; i += 256) {
        int g = i >> 6, c = i & 63;
        float acc = b1[c];
        #pragma unroll
        for (int k = 0; k < 64; ++k) acc += sp[g][k] * w1[k * 64 + c];
        sz[g][c] = fmaxf(acc, 0.f);
    }
    __syncthreads();
    if (t < 64) {
        float acc = b2[0];
        #pragma unroll
        for (int c = 0; c < 64; ++c) acc += sz[t][c] * w2[c];
        out[t] = 1.f / (1.f + __expf(-acc));
    }
}

extern "C" void kernel_launch(void* const* d_in, const int* in_sizes, int n_in,
                              void* d_out, int out_size, void* d_ws, size_t ws_size,
                              hipStream_t stream) {
    const float* x     = (const float*)d_in[0];
    const int*   ei    = (const int*)d_in[1];   // [2, NE] flat: src row then dst row
    const int*   batch = (const int*)d_in[2];
    const float* W     = (const float*)d_in[3];
    const float* att_s = (const float*)d_in[4];
    const float* att_d = (const float*)d_in[5];
    const float* bias  = (const float*)d_in[6];
    const float* w1    = (const float*)d_in[7];
    const float* b1    = (const float*)d_in[8];
    const float* w2    = (const float*)d_in[9];
    const float* b2    = (const float*)d_in[10];
    float* out = (float*)d_out;

    const int* src = ei;
    const int* dst = ei + NE;

    // workspace layout (floats / ints)
    float* h      = (float*)d_ws;               // NN*64
    float* as_    = h + (size_t)NN * HID;       // NN
    float* ad_    = as_ + NN;                   // NN
    float* g      = ad_ + NN;                   // NN*64
    float* pooled = g + (size_t)NN * HID;       // NG*64
    float* cntp   = pooled + NG * HID;          // NG
    int*   deg    = (int*)(cntp + NG);          // NN
    int*   cursor = deg + NN;                   // NN
    int*   csr    = cursor + NN;                // NE

    // zero: deg + pooled + cnt (fresh every call — deterministic)
    hipMemsetAsync(deg, 0, NN * sizeof(int), stream);
    hipMemsetAsync(pooled, 0, (NG * HID + NG) * sizeof(float), stream);

    k_xw<<<(NN + 3) / 4, 256, 0, stream>>>(x, W, att_s, att_d, h, as_, ad_);

    k_deg <<<(NE + 255) / 256, 256, 0, stream>>>(dst, deg);
    k_scan<<<1, 256, 0, stream>>>(deg, cursor);
    k_fill<<<(NE + 255) / 256, 256, 0, stream>>>(src, dst, cursor, csr);

    k_gather<<<(NN + 3) / 4, 256, 0, stream>>>(csr, cursor, deg, h, as_, ad_, bias, g);

    k_node<<<(NN / (4 * NPW)) + 1, 256, 0, stream>>>(g, batch, pooled, cntp);

    k_final<<<1, 256, 0, stream>>>(pooled, cntp, w1, b1, w2, b2, out);
}

// Round 5
// 247.259 us; speedup vs baseline: 2.7480x; 1.3124x over previous
//
#include <hip/hip_runtime.h>

#define NN 50000
#define NE 800000
#define NG 64
#define HID 64
#define NEG 0.2f
#define NPW 64          // nodes per wave in k_node
#define SCAN_B 196      // ceil(NN/256)

// ---------------- K1: h = x @ W ; a_s = h.att_src ; a_d = h.att_dst --------
__global__ __launch_bounds__(256)
void k_xw(const float* __restrict__ x, const float* __restrict__ W,
          const float* __restrict__ att_s, const float* __restrict__ att_d,
          float* __restrict__ h, float* __restrict__ as_, float* __restrict__ ad_) {
    __shared__ float sW[64][64];   // W[k][c]; lane-varying c => conflict-free
    int t = threadIdx.x;
    for (int i = t; i < 4096; i += 256) sW[i >> 6][i & 63] = W[i];
    __syncthreads();
    int wave = t >> 6, lane = t & 63;
    int row = blockIdx.x * 4 + wave;
    if (row >= NN) return;
    float xk = x[row * 64 + lane];         // coalesced; then broadcast
    float acc = 0.f;
    #pragma unroll
    for (int k = 0; k < 64; ++k)
        acc += __shfl(xk, k, 64) * sW[k][lane];
    h[row * 64 + lane] = acc;
    float ps = acc * att_s[lane];
    float pd = acc * att_d[lane];
    #pragma unroll
    for (int m = 32; m >= 1; m >>= 1) {
        ps += __shfl_xor(ps, m, 64);
        pd += __shfl_xor(pd, m, 64);
    }
    if (lane == 0) { as_[row] = ps; ad_[row] = pd; }
}

// ---------------- CSR build: degree count --------------------------------
__global__ __launch_bounds__(256)
void k_deg(const int* __restrict__ dst, int* __restrict__ deg) {
    int e = blockIdx.x * 256 + threadIdx.x;
    if (e < NE) atomicAdd(&deg[dst[e]], 1);
}

// ---------------- hierarchical scan (3 stages, all parallel) --------------
__global__ __launch_bounds__(256)
void k_scan1(const int* __restrict__ deg, int* __restrict__ bsum) {
    int t = threadIdx.x;
    int i = blockIdx.x * 256 + t;
    int v = (i < NN) ? deg[i] : 0;
    #pragma unroll
    for (int m = 32; m >= 1; m >>= 1) v += __shfl_xor(v, m, 64);
    __shared__ int ws[4];
    if ((t & 63) == 0) ws[t >> 6] = v;
    __syncthreads();
    if (t == 0) bsum[blockIdx.x] = ws[0] + ws[1] + ws[2] + ws[3];
}

__global__ __launch_bounds__(256)
void k_scan2(int* __restrict__ bsum) {
    __shared__ int sh[256];
    int t = threadIdx.x;
    int v = (t < SCAN_B) ? bsum[t] : 0;
    sh[t] = v;
    __syncthreads();
    for (int off = 1; off < 256; off <<= 1) {
        int u = (t >= off) ? sh[t - off] : 0;
        __syncthreads();
        sh[t] += u;
        __syncthreads();
    }
    if (t < SCAN_B) bsum[t] = sh[t] - v;          // exclusive
}

__global__ __launch_bounds__(256)
void k_scan3(const int* __restrict__ deg, const int* __restrict__ bsum,
             int* __restrict__ cursor) {
    __shared__ int sh[256];
    int t = threadIdx.x;
    int i = blockIdx.x * 256 + t;
    int v = (i < NN) ? deg[i] : 0;
    sh[t] = v;
    __syncthreads();
    for (int off = 1; off < 256; off <<= 1) {
        int u = (t >= off) ? sh[t - off] : 0;
        __syncthreads();
        sh[t] += u;
        __syncthreads();
    }
    if (i < NN) cursor[i] = bsum[blockIdx.x] + sh[t] - v;   // exclusive start
}

// ---------------- CSR build: fill (cursor advances to end offset) ---------
__global__ __launch_bounds__(256)
void k_fill(const int* __restrict__ src, const int* __restrict__ dst,
            int* __restrict__ cursor, int* __restrict__ csr) {
    int e = blockIdx.x * 256 + threadIdx.x;
    if (e < NE) {
        int p = atomicAdd(&cursor[dst[e]], 1);
        csr[p] = src[e];
    }
}

// ---------------- K2': gather per dst node (no atomics) -------------------
// g[d] = relu( (sum_s h[s]*exp(lrelu(as[s]+ad[d]))) / (sum exp) + bias )
// self-loop folded in analytically. After k_fill, cursor[d] = end offset.
__global__ __launch_bounds__(256)
void k_gather(const int* __restrict__ csr, const int* __restrict__ cursor,
              const int* __restrict__ deg, const float* __restrict__ h,
              const float* __restrict__ as_, const float* __restrict__ ad_,
              const float* __restrict__ bias, float* __restrict__ g) {
    int t = threadIdx.x;
    int wave = t >> 6, lane = t & 63;
    int d = blockIdx.x * 4 + wave;
    if (d >= NN) return;
    int cend = cursor[d];
    int nd   = deg[d];
    int cbeg = cend - nd;
    float adv = ad_[d];
    // self loop (s = d)
    float e0 = as_[d] + adv;
    e0 = e0 >= 0.f ? e0 : NEG * e0;
    float ex0 = __expf(e0);
    float den = ex0;
    float acc = h[(size_t)d * 64 + lane] * ex0;
    #pragma unroll 4
    for (int c = cbeg; c < cend; ++c) {
        int s = csr[c];                           // wave-uniform (broadcast)
        float av = as_[s] + adv;
        av = av >= 0.f ? av : NEG * av;
        float ex = __expf(av);
        den += ex;
        acc += h[(size_t)s * 64 + lane] * ex;     // 256B coalesced gather
    }
    g[(size_t)d * 64 + lane] = fmaxf(acc / den + bias[lane], 0.f);
}

// ---------------- K3: pooled partial sums (batch sorted, run-length) ------
__global__ __launch_bounds__(256)
void k_node(const float* __restrict__ g, const int* __restrict__ batch,
            float* __restrict__ pooled, float* __restrict__ cnt) {
    int t = threadIdx.x;
    int wave = t >> 6, lane = t & 63;
    int n0 = (blockIdx.x * 4 + wave) * NPW;
    if (n0 >= NN) return;
    int n1 = n0 + NPW; if (n1 > NN) n1 = NN;
    float acc = 0.f, c = 0.f;
    int cur = batch[n0];
    for (int n = n0; n < n1; ++n) {
        int gr = batch[n];
        if (gr != cur) {
            atomicAdd(&pooled[cur * 64 + lane], acc);
            if (lane == 0) atomicAdd(&cnt[cur], c);
            acc = 0.f; c = 0.f; cur = gr;
        }
        acc += g[(size_t)n * 64 + lane];
        c += 1.f;
    }
    atomicAdd(&pooled[cur * 64 + lane], acc);
    if (lane == 0) atomicAdd(&cnt[cur], c);
}

// ---------------- K4: mean + MLP + sigmoid (single block) ------------------
__global__ __launch_bounds__(256)
void k_final(const float* __restrict__ pooled, const float* __restrict__ cnt,
             const float* __restrict__ w1, const float* __restrict__ b1,
             const float* __restrict__ w2, const float* __restrict__ b2,
             float* __restrict__ out) {
    __shared__ float sp[64][65];
    __shared__ float sz[64][65];
    int t = threadIdx.x;
    for (int i = t; i < 4096; i += 256) {
        int g = i >> 6, c = i & 63;
        sp[g][c] = pooled[i] / fmaxf(cnt[g], 1.0f);
    }
    __syncthreads();
    for (int i = t; i < 4096; i += 256) {
        int g = i >> 6, c = i & 63;
        float acc = b1[c];
        #pragma unroll
        for (int k = 0; k < 64; ++k) acc += sp[g][k] * w1[k * 64 + c];
        sz[g][c] = fmaxf(acc, 0.f);
    }
    __syncthreads();
    if (t < 64) {
        float acc = b2[0];
        #pragma unroll
        for (int c = 0; c < 64; ++c) acc += sz[t][c] * w2[c];
        out[t] = 1.f / (1.f + __expf(-acc));
    }
}

extern "C" void kernel_launch(void* const* d_in, const int* in_sizes, int n_in,
                              void* d_out, int out_size, void* d_ws, size_t ws_size,
                              hipStream_t stream) {
    const float* x     = (const float*)d_in[0];
    const int*   ei    = (const int*)d_in[1];   // [2, NE] flat: src row then dst row
    const int*   batch = (const int*)d_in[2];
    const float* W     = (const float*)d_in[3];
    const float* att_s = (const float*)d_in[4];
    const float* att_d = (const float*)d_in[5];
    const float* bias  = (const float*)d_in[6];
    const float* w1    = (const float*)d_in[7];
    const float* b1    = (const float*)d_in[8];
    const float* w2    = (const float*)d_in[9];
    const float* b2    = (const float*)d_in[10];
    float* out = (float*)d_out;

    const int* src = ei;
    const int* dst = ei + NE;

    // workspace layout (floats / ints)
    float* h      = (float*)d_ws;               // NN*64
    float* as_    = h + (size_t)NN * HID;       // NN
    float* ad_    = as_ + NN;                   // NN
    float* g      = ad_ + NN;                   // NN*64
    float* pooled = g + (size_t)NN * HID;       // NG*64
    float* cntp   = pooled + NG * HID;          // NG
    int*   deg    = (int*)(cntp + NG);          // NN
    int*   cursor = deg + NN;                   // NN
    int*   csr    = cursor + NN;                // NE
    int*   bsum   = csr + NE;                   // SCAN_B

    // zero: deg + pooled + cnt (fresh every call — deterministic)
    hipMemsetAsync(deg, 0, NN * sizeof(int), stream);
    hipMemsetAsync(pooled, 0, (NG * HID + NG) * sizeof(float), stream);

    k_xw<<<(NN + 3) / 4, 256, 0, stream>>>(x, W, att_s, att_d, h, as_, ad_);

    k_deg  <<<(NE + 255) / 256, 256, 0, stream>>>(dst, deg);
    k_scan1<<<SCAN_B, 256, 0, stream>>>(deg, bsum);
    k_scan2<<<1, 256, 0, stream>>>(bsum);
    k_scan3<<<SCAN_B, 256, 0, stream>>>(deg, bsum, cursor);
    k_fill <<<(NE + 255) / 256, 256, 0, stream>>>(src, dst, cursor, csr);

    k_gather<<<(NN + 3) / 4, 256, 0, stream>>>(csr, cursor, deg, h, as_, ad_, bias, g);

    k_node<<<(NN / (4 * NPW)) + 1, 256, 0, stream>>>(g, batch, pooled, cntp);

    k_final<<<1, 256, 0, stream>>>(pooled, cntp, w1, b1, w2, b2, out);
}

// Round 6
// 216.156 us; speedup vs baseline: 3.1434x; 1.1439x over previous
//
#include <hip/hip_runtime.h>

#define NN 50000
#define NE 800000
#define NG 64
#define HID 64
#define NEG 0.2f
#define NPW 64          // nodes per wave in k_node
#define SCAN_B 196      // ceil(NN/256)

// ---------------- K1: h = x @ W ; a_s = h.att_src ; a_d = h.att_dst --------
// Register-tiled f32 GEMM: block = 16x16 threads, 64-row tile, 4x4 micro-tile
// per thread. Per k-step: 2 x ds_read_b128 + 16 FMA (was 2 LDS ops per FMA).
__global__ __launch_bounds__(256)
void k_xw(const float* __restrict__ x, const float* __restrict__ W,
          const float* __restrict__ att_s, const float* __restrict__ att_d,
          float* __restrict__ h, float* __restrict__ as_, float* __restrict__ ad_) {
    __shared__ __align__(16) float sW[64][64];    // [k][c]
    __shared__ __align__(16) float sxT[64][68];   // [k][r], stride 68 keeps
                                                  // float4 16B-aligned, <=2-way banks
    int t = threadIdx.x;
    int r0 = blockIdx.x * 64;
    for (int i = t; i < 4096; i += 256) sW[i >> 6][i & 63] = W[i];
    for (int i = t; i < 4096; i += 256) {
        int r = i >> 6, c = i & 63;
        int gr = r0 + r; if (gr >= NN) gr = NN - 1;   // clamp; stores guarded
        sxT[c][r] = x[(size_t)gr * 64 + c];
    }
    __syncthreads();

    int tx = t & 15, ty = t >> 4;                 // ty 0..15 (4 per wave)
    float4 asv = ((const float4*)att_s)[tx];
    float4 adv = ((const float4*)att_d)[tx];

    float acc[4][4] = {};
    #pragma unroll
    for (int k = 0; k < 64; ++k) {
        float4 a = *(const float4*)&sxT[k][4 * ty];   // rows 4ty..4ty+3
        float4 b = *(const float4*)&sW[k][4 * tx];    // cols 4tx..4tx+3
        float av[4] = {a.x, a.y, a.z, a.w};
        float bv[4] = {b.x, b.y, b.z, b.w};
        #pragma unroll
        for (int i = 0; i < 4; ++i)
            #pragma unroll
            for (int j = 0; j < 4; ++j)
                acc[i][j] += av[i] * bv[j];
    }

    #pragma unroll
    for (int i = 0; i < 4; ++i) {
        int r = r0 + 4 * ty + i;
        if (r < NN) {
            float4 hv = make_float4(acc[i][0], acc[i][1], acc[i][2], acc[i][3]);
            *(float4*)&h[(size_t)r * 64 + 4 * tx] = hv;
            float ps = acc[i][0]*asv.x + acc[i][1]*asv.y + acc[i][2]*asv.z + acc[i][3]*asv.w;
            float pd = acc[i][0]*adv.x + acc[i][1]*adv.y + acc[i][2]*adv.z + acc[i][3]*adv.w;
            #pragma unroll
            for (int m = 1; m <= 8; m <<= 1) {    // reduce over the 16 tx lanes
                ps += __shfl_xor(ps, m, 64);
                pd += __shfl_xor(pd, m, 64);
            }
            if (tx == 0) { as_[r] = ps; ad_[r] = pd; }
        }
    }
}

// ---------------- CSR build: degree count --------------------------------
__global__ __launch_bounds__(256)
void k_deg(const int* __restrict__ dst, int* __restrict__ deg) {
    int e = blockIdx.x * 256 + threadIdx.x;
    if (e < NE) atomicAdd(&deg[dst[e]], 1);
}

// ---------------- hierarchical scan (3 stages, all parallel) --------------
__global__ __launch_bounds__(256)
void k_scan1(const int* __restrict__ deg, int* __restrict__ bsum) {
    int t = threadIdx.x;
    int i = blockIdx.x * 256 + t;
    int v = (i < NN) ? deg[i] : 0;
    #pragma unroll
    for (int m = 32; m >= 1; m >>= 1) v += __shfl_xor(v, m, 64);
    __shared__ int ws[4];
    if ((t & 63) == 0) ws[t >> 6] = v;
    __syncthreads();
    if (t == 0) bsum[blockIdx.x] = ws[0] + ws[1] + ws[2] + ws[3];
}

__global__ __launch_bounds__(256)
void k_scan2(int* __restrict__ bsum) {
    __shared__ int sh[256];
    int t = threadIdx.x;
    int v = (t < SCAN_B) ? bsum[t] : 0;
    sh[t] = v;
    __syncthreads();
    for (int off = 1; off < 256; off <<= 1) {
        int u = (t >= off) ? sh[t - off] : 0;
        __syncthreads();
        sh[t] += u;
        __syncthreads();
    }
    if (t < SCAN_B) bsum[t] = sh[t] - v;          // exclusive
}

__global__ __launch_bounds__(256)
void k_scan3(const int* __restrict__ deg, const int* __restrict__ bsum,
             int* __restrict__ cursor) {
    __shared__ int sh[256];
    int t = threadIdx.x;
    int i = blockIdx.x * 256 + t;
    int v = (i < NN) ? deg[i] : 0;
    sh[t] = v;
    __syncthreads();
    for (int off = 1; off < 256; off <<= 1) {
        int u = (t >= off) ? sh[t - off] : 0;
        __syncthreads();
        sh[t] += u;
        __syncthreads();
    }
    if (i < NN) cursor[i] = bsum[blockIdx.x] + sh[t] - v;   // exclusive start
}

// ---------------- CSR build: fill (cursor advances to end offset) ---------
__global__ __launch_bounds__(256)
void k_fill(const int* __restrict__ src, const int* __restrict__ dst,
            int* __restrict__ cursor, int* __restrict__ csr) {
    int e = blockIdx.x * 256 + threadIdx.x;
    if (e < NE) {
        int p = atomicAdd(&cursor[dst[e]], 1);
        csr[p] = src[e];
    }
}

// ---------------- K2': gather per dst node (no atomics) -------------------
__global__ __launch_bounds__(256)
void k_gather(const int* __restrict__ csr, const int* __restrict__ cursor,
              const int* __restrict__ deg, const float* __restrict__ h,
              const float* __restrict__ as_, const float* __restrict__ ad_,
              const float* __restrict__ bias, float* __restrict__ g) {
    int t = threadIdx.x;
    int wave = t >> 6, lane = t & 63;
    int d = blockIdx.x * 4 + wave;
    if (d >= NN) return;
    int cend = cursor[d];
    int nd   = deg[d];
    int cbeg = cend - nd;
    float adv = ad_[d];
    // self loop (s = d)
    float e0 = as_[d] + adv;
    e0 = e0 >= 0.f ? e0 : NEG * e0;
    float ex0 = __expf(e0);
    float den = ex0;
    float acc = h[(size_t)d * 64 + lane] * ex0;
    #pragma unroll 4
    for (int c = cbeg; c < cend; ++c) {
        int s = csr[c];                           // wave-uniform (broadcast)
        float av = as_[s] + adv;
        av = av >= 0.f ? av : NEG * av;
        float ex = __expf(av);
        den += ex;
        acc += h[(size_t)s * 64 + lane] * ex;     // 256B coalesced gather
    }
    g[(size_t)d * 64 + lane] = fmaxf(acc / den + bias[lane], 0.f);
}

// ---------------- K3: pooled partial sums (batch sorted, run-length) ------
__global__ __launch_bounds__(256)
void k_node(const float* __restrict__ g, const int* __restrict__ batch,
            float* __restrict__ pooled, float* __restrict__ cnt) {
    int t = threadIdx.x;
    int wave = t >> 6, lane = t & 63;
    int n0 = (blockIdx.x * 4 + wave) * NPW;
    if (n0 >= NN) return;
    int n1 = n0 + NPW; if (n1 > NN) n1 = NN;
    float acc = 0.f, c = 0.f;
    int cur = batch[n0];
    for (int n = n0; n < n1; ++n) {
        int gr = batch[n];
        if (gr != cur) {
            atomicAdd(&pooled[cur * 64 + lane], acc);
            if (lane == 0) atomicAdd(&cnt[cur], c);
            acc = 0.f; c = 0.f; cur = gr;
        }
        acc += g[(size_t)n * 64 + lane];
        c += 1.f;
    }
    atomicAdd(&pooled[cur * 64 + lane], acc);
    if (lane == 0) atomicAdd(&cnt[cur], c);
}

// ---------------- K4: mean + MLP + sigmoid (single block) ------------------
__global__ __launch_bounds__(256)
void k_final(const float* __restrict__ pooled, const float* __restrict__ cnt,
             const float* __restrict__ w1, const float* __restrict__ b1,
             const float* __restrict__ w2, const float* __restrict__ b2,
             float* __restrict__ out) {
    __shared__ float sp[64][65];
    __shared__ float sz[64][65];
    int t = threadIdx.x;
    for (int i = t; i < 4096; i += 256) {
        int g = i >> 6, c = i & 63;
        sp[g][c] = pooled[i] / fmaxf(cnt[g], 1.0f);
    }
    __syncthreads();
    for (int i = t; i < 4096; i += 256) {
        int g = i >> 6, c = i & 63;
        float acc = b1[c];
        #pragma unroll
        for (int k = 0; k < 64; ++k) acc += sp[g][k] * w1[k * 64 + c];
        sz[g][c] = fmaxf(acc, 0.f);
    }
    __syncthreads();
    if (t < 64) {
        float acc = b2[0];
        #pragma unroll
        for (int c = 0; c < 64; ++c) acc += sz[t][c] * w2[c];
        out[t] = 1.f / (1.f + __expf(-acc));
    }
}

extern "C" void kernel_launch(void* const* d_in, const int* in_sizes, int n_in,
                              void* d_out, int out_size, void* d_ws, size_t ws_size,
                              hipStream_t stream) {
    const float* x     = (const float*)d_in[0];
    const int*   ei    = (const int*)d_in[1];   // [2, NE] flat: src row then dst row
    const int*   batch = (const int*)d_in[2];
    const float* W     = (const float*)d_in[3];
    const float* att_s = (const float*)d_in[4];
    const float* att_d = (const float*)d_in[5];
    const float* bias  = (const float*)d_in[6];
    const float* w1    = (const float*)d_in[7];
    const float* b1    = (const float*)d_in[8];
    const float* w2    = (const float*)d_in[9];
    const float* b2    = (const float*)d_in[10];
    float* out = (float*)d_out;

    const int* src = ei;
    const int* dst = ei + NE;

    // workspace layout (floats / ints)
    float* h      = (float*)d_ws;               // NN*64
    float* as_    = h + (size_t)NN * HID;       // NN
    float* ad_    = as_ + NN;                   // NN
    float* g      = ad_ + NN;                   // NN*64
    float* pooled = g + (size_t)NN * HID;       // NG*64
    float* cntp   = pooled + NG * HID;          // NG
    int*   deg    = (int*)(cntp + NG);          // NN
    int*   cursor = deg + NN;                   // NN
    int*   csr    = cursor + NN;                // NE
    int*   bsum   = csr + NE;                   // SCAN_B

    hipMemsetAsync(deg, 0, NN * sizeof(int), stream);
    hipMemsetAsync(pooled, 0, (NG * HID + NG) * sizeof(float), stream);

    k_xw<<<(NN + 63) / 64, 256, 0, stream>>>(x, W, att_s, att_d, h, as_, ad_);

    k_deg  <<<(NE + 255) / 256, 256, 0, stream>>>(dst, deg);
    k_scan1<<<SCAN_B, 256, 0, stream>>>(deg, bsum);
    k_scan2<<<1, 256, 0, stream>>>(bsum);
    k_scan3<<<SCAN_B, 256, 0, stream>>>(deg, bsum, cursor);
    k_fill <<<(NE + 255) / 256, 256, 0, stream>>>(src, dst, cursor, csr);

    k_gather<<<(NN + 3) / 4, 256, 0, stream>>>(csr, cursor, deg, h, as_, ad_, bias, g);

    k_node<<<(NN / (4 * NPW)) + 1, 256, 0, stream>>>(g, batch, pooled, cntp);

    k_final<<<1, 256, 0, stream>>>(pooled, cntp, w1, b1, w2, b2, out);
}

// Round 8
// 150.175 us; speedup vs baseline: 4.5244x; 1.4394x over previous
//
#include <hip/hip_runtime.h>

#define NN 50000
#define NE 800000
#define NG 64
#define HID 64
#define NEG 0.2f
#define NPW 64          // nodes per wave in k_node
#define NBUCK 196       // ceil(NN/256) coarse buckets (dst>>8)
#define CHUNK 2048      // edges per k_bucket block
#define KC_CAP 6144     // per-bucket ebuf segment (mean 4096 + 32 sigma)

// ---------------- K1: h = x @ W ; a_s = h.att_src ; a_d = h.att_dst --------
// Register-tiled f32 GEMM: block = 16x16 threads, 64-row tile, 4x4 micro-tile.
__global__ __launch_bounds__(256)
void k_xw(const float* __restrict__ x, const float* __restrict__ W,
          const float* __restrict__ att_s, const float* __restrict__ att_d,
          float* __restrict__ h, float* __restrict__ as_, float* __restrict__ ad_) {
    __shared__ __align__(16) float sW[64][64];    // [k][c]
    __shared__ __align__(16) float sxT[64][68];   // [k][r]
    int t = threadIdx.x;
    int r0 = blockIdx.x * 64;
    for (int i = t; i < 4096; i += 256) sW[i >> 6][i & 63] = W[i];
    for (int i = t; i < 4096; i += 256) {
        int r = i >> 6, c = i & 63;
        int gr = r0 + r; if (gr >= NN) gr = NN - 1;
        sxT[c][r] = x[(size_t)gr * 64 + c];
    }
    __syncthreads();

    int tx = t & 15, ty = t >> 4;
    float4 asv = ((const float4*)att_s)[tx];
    float4 adv = ((const float4*)att_d)[tx];

    float acc[4][4] = {};
    #pragma unroll
    for (int k = 0; k < 64; ++k) {
        float4 a = *(const float4*)&sxT[k][4 * ty];
        float4 b = *(const float4*)&sW[k][4 * tx];
        float av[4] = {a.x, a.y, a.z, a.w};
        float bv[4] = {b.x, b.y, b.z, b.w};
        #pragma unroll
        for (int i = 0; i < 4; ++i)
            #pragma unroll
            for (int j = 0; j < 4; ++j)
                acc[i][j] += av[i] * bv[j];
    }

    #pragma unroll
    for (int i = 0; i < 4; ++i) {
        int r = r0 + 4 * ty + i;
        if (r < NN) {
            float4 hv = make_float4(acc[i][0], acc[i][1], acc[i][2], acc[i][3]);
            *(float4*)&h[(size_t)r * 64 + 4 * tx] = hv;
            float ps = acc[i][0]*asv.x + acc[i][1]*asv.y + acc[i][2]*asv.z + acc[i][3]*asv.w;
            float pd = acc[i][0]*adv.x + acc[i][1]*adv.y + acc[i][2]*adv.z + acc[i][3]*adv.w;
            #pragma unroll
            for (int m = 1; m <= 8; m <<= 1) {
                ps += __shfl_xor(ps, m, 64);
                pd += __shfl_xor(pd, m, 64);
            }
            if (tx == 0) { as_[r] = ps; ad_[r] = pd; }
        }
    }
}

// ---------------- Pass B: blockwise bucket sort (dst>>8) ------------------
// Bucket b owns ebuf[b*KC_CAP ..]; blocks reserve sub-segments via gcur[b].
// All global writes are coalesced runs; atomics: 1 per (block,bucket).
__global__ __launch_bounds__(256)
void k_bucket(const int* __restrict__ src, const int* __restrict__ dst,
              int* __restrict__ gcur, int* __restrict__ ebuf) {
    __shared__ int lhist[256], lscan[256], loff[256], lcur[256], gbase[256];
    __shared__ int lsort[CHUNK];
    __shared__ unsigned char lbuck[CHUNK];
    int t = threadIdx.x;
    int base = blockIdx.x * CHUNK;
    int cnt = NE - base; if (cnt > CHUNK) cnt = CHUNK; if (cnt < 0) cnt = 0;

    int ds[8], ss[8];
    int nv = 0;
    #pragma unroll
    for (int j = 0; j < 8; ++j) {
        int e = base + j * 256 + t;
        if (e < NE) { ds[nv] = dst[e]; ss[nv] = src[e]; ++nv; }
    }
    lhist[t] = 0;
    __syncthreads();
    for (int j = 0; j < nv; ++j) atomicAdd(&lhist[ds[j] >> 8], 1);
    __syncthreads();
    lscan[t] = lhist[t];
    __syncthreads();
    for (int off = 1; off < 256; off <<= 1) {
        int u = (t >= off) ? lscan[t - off] : 0;
        __syncthreads();
        lscan[t] += u;
        __syncthreads();
    }
    loff[t] = lscan[t] - lhist[t];   // exclusive
    lcur[t] = 0;
    __syncthreads();
    for (int j = 0; j < nv; ++j) {
        int b = ds[j] >> 8;
        int r = atomicAdd(&lcur[b], 1);
        int slot = loff[b] + r;
        lsort[slot] = (ss[j] << 8) | (ds[j] & 255);   // src<50000 fits in 24b
        lbuck[slot] = (unsigned char)b;
    }
    if (t < NBUCK) {
        int c = lhist[t];
        gbase[t] = c ? atomicAdd(&gcur[t], c) : 0;    // offset WITHIN bucket t
    }
    __syncthreads();
    for (int i = t; i < cnt; i += 256) {
        int b = lbuck[i];
        ebuf[b * KC_CAP + gbase[b] + (i - loff[b])] = lsort[i];  // FIX: segmented
    }
}

// ---------------- Pass C: exact CSR within each bucket --------------------
// One block per bucket: per-dst LDS histogram + scan + scatter; coalesced
// csr write; emits deg[d] and cursor[d] (= end offset) for k_gather.
__global__ __launch_bounds__(256)
void k_csr(const int* __restrict__ gcur, const int* __restrict__ ebuf,
           int* __restrict__ csr, int* __restrict__ cursor, int* __restrict__ deg) {
    __shared__ int lhist[256], lscan[256], loff[256], lcur[256], bscan[256];
    __shared__ int lsrc[KC_CAP];
    int t = threadIdx.x;
    int b = blockIdx.x;

    bscan[t] = (t < NBUCK) ? gcur[t] : 0;     // bucket sizes
    __syncthreads();
    for (int off = 1; off < 256; off <<= 1) {
        int u = (t >= off) ? bscan[t - off] : 0;
        __syncthreads();
        bscan[t] += u;
        __syncthreads();
    }
    int sz = gcur[b];                          // this bucket's edge count
    int gb = bscan[b] - sz;                    // dense CSR base (exclusive)
    const int* seg = ebuf + b * KC_CAP;        // FIX: segmented read

    lhist[t] = 0;
    __syncthreads();
    for (int i = t; i < sz; i += 256)
        atomicAdd(&lhist[seg[i] & 255], 1);
    __syncthreads();
    lscan[t] = lhist[t];
    __syncthreads();
    for (int off = 1; off < 256; off <<= 1) {
        int u = (t >= off) ? lscan[t - off] : 0;
        __syncthreads();
        lscan[t] += u;
        __syncthreads();
    }
    loff[t] = lscan[t] - lhist[t];
    lcur[t] = 0;
    __syncthreads();
    for (int i = t; i < sz; i += 256) {
        int w = seg[i];
        int dl = w & 255;
        int r = atomicAdd(&lcur[dl], 1);
        lsrc[loff[dl] + r] = w >> 8;
    }
    __syncthreads();
    for (int i = t; i < sz; i += 256)
        csr[gb + i] = lsrc[i];
    int d = b * 256 + t;
    if (d < NN) {
        deg[d] = lhist[t];
        cursor[d] = gb + loff[t] + lhist[t];   // end offset
    }
}

// ---------------- K2': gather per dst node (no atomics) -------------------
__global__ __launch_bounds__(256)
void k_gather(const int* __restrict__ csr, const int* __restrict__ cursor,
              const int* __restrict__ deg, const float* __restrict__ h,
              const float* __restrict__ as_, const float* __restrict__ ad_,
              const float* __restrict__ bias, float* __restrict__ g) {
    int t = threadIdx.x;
    int wave = t >> 6, lane = t & 63;
    int d = blockIdx.x * 4 + wave;
    if (d >= NN) return;
    int cend = cursor[d];
    int nd   = deg[d];
    int cbeg = cend - nd;
    float adv = ad_[d];
    float e0 = as_[d] + adv;
    e0 = e0 >= 0.f ? e0 : NEG * e0;
    float ex0 = __expf(e0);
    float den = ex0;
    float acc = h[(size_t)d * 64 + lane] * ex0;
    #pragma unroll 4
    for (int c = cbeg; c < cend; ++c) {
        int s = csr[c];
        float av = as_[s] + adv;
        av = av >= 0.f ? av : NEG * av;
        float ex = __expf(av);
        den += ex;
        acc += h[(size_t)s * 64 + lane] * ex;
    }
    g[(size_t)d * 64 + lane] = fmaxf(acc / den + bias[lane], 0.f);
}

// ---------------- K3: pooled partial sums (batch sorted, run-length) ------
__global__ __launch_bounds__(256)
void k_node(const float* __restrict__ g, const int* __restrict__ batch,
            float* __restrict__ pooled, float* __restrict__ cnt) {
    int t = threadIdx.x;
    int wave = t >> 6, lane = t & 63;
    int n0 = (blockIdx.x * 4 + wave) * NPW;
    if (n0 >= NN) return;
    int n1 = n0 + NPW; if (n1 > NN) n1 = NN;
    float acc = 0.f, c = 0.f;
    int cur = batch[n0];
    for (int n = n0; n < n1; ++n) {
        int gr = batch[n];
        if (gr != cur) {
            atomicAdd(&pooled[cur * 64 + lane], acc);
            if (lane == 0) atomicAdd(&cnt[cur], c);
            acc = 0.f; c = 0.f; cur = gr;
        }
        acc += g[(size_t)n * 64 + lane];
        c += 1.f;
    }
    atomicAdd(&pooled[cur * 64 + lane], acc);
    if (lane == 0) atomicAdd(&cnt[cur], c);
}

// ---------------- K4: mean + MLP + sigmoid (single block) ------------------
__global__ __launch_bounds__(256)
void k_final(const float* __restrict__ pooled, const float* __restrict__ cnt,
             const float* __restrict__ w1, const float* __restrict__ b1,
             const float* __restrict__ w2, const float* __restrict__ b2,
             float* __restrict__ out) {
    __shared__ float sp[64][65];
    __shared__ float sz[64][65];
    int t = threadIdx.x;
    for (int i = t; i < 4096; i += 256) {
        int g = i >> 6, c = i & 63;
        sp[g][c] = pooled[i] / fmaxf(cnt[g], 1.0f);
    }
    __syncthreads();
    for (int i = t; i < 4096; i += 256) {
        int g = i >> 6, c = i & 63;
        float acc = b1[c];
        #pragma unroll
        for (int k = 0; k < 64; ++k) acc += sp[g][k] * w1[k * 64 + c];
        sz[g][c] = fmaxf(acc, 0.f);
    }
    __syncthreads();
    if (t < 64) {
        float acc = b2[0];
        #pragma unroll
        for (int c = 0; c < 64; ++c) acc += sz[t][c] * w2[c];
        out[t] = 1.f / (1.f + __expf(-acc));
    }
}

extern "C" void kernel_launch(void* const* d_in, const int* in_sizes, int n_in,
                              void* d_out, int out_size, void* d_ws, size_t ws_size,
                              hipStream_t stream) {
    const float* x     = (const float*)d_in[0];
    const int*   ei    = (const int*)d_in[1];   // [2, NE] flat: src row then dst row
    const int*   batch = (const int*)d_in[2];
    const float* W     = (const float*)d_in[3];
    const float* att_s = (const float*)d_in[4];
    const float* att_d = (const float*)d_in[5];
    const float* bias  = (const float*)d_in[6];
    const float* w1    = (const float*)d_in[7];
    const float* b1    = (const float*)d_in[8];
    const float* w2    = (const float*)d_in[9];
    const float* b2    = (const float*)d_in[10];
    float* out = (float*)d_out;

    const int* src = ei;
    const int* dst = ei + NE;

    // workspace layout (floats / ints)
    float* h      = (float*)d_ws;               // NN*64
    float* as_    = h + (size_t)NN * HID;       // NN
    float* ad_    = as_ + NN;                   // NN
    float* g      = ad_ + NN;                   // NN*64  (ebuf aliases this)
    float* pooled = g + (size_t)NN * HID;       // NG*64
    float* cntp   = pooled + NG * HID;          // NG
    int*   deg    = (int*)(cntp + NG);          // NN
    int*   cursor = deg + NN;                   // NN
    int*   csr    = cursor + NN;                // NE
    int*   gcur   = csr + NE;                   // NBUCK
    int*   ebuf   = (int*)g;                    // NBUCK*KC_CAP (= 4.6MB < NN*64*4)
                                                // lifetime: k_bucket..k_csr only

    hipMemsetAsync(gcur, 0, NBUCK * sizeof(int), stream);
    hipMemsetAsync(pooled, 0, (NG * HID + NG) * sizeof(float), stream);

    k_xw<<<(NN + 63) / 64, 256, 0, stream>>>(x, W, att_s, att_d, h, as_, ad_);

    k_bucket<<<(NE + CHUNK - 1) / CHUNK, 256, 0, stream>>>(src, dst, gcur, ebuf);
    k_csr<<<NBUCK, 256, 0, stream>>>(gcur, ebuf, csr, cursor, deg);

    k_gather<<<(NN + 3) / 4, 256, 0, stream>>>(csr, cursor, deg, h, as_, ad_, bias, g);

    k_node<<<(NN / (4 * NPW)) + 1, 256, 0, stream>>>(g, batch, pooled, cntp);

    k_final<<<1, 256, 0, stream>>>(pooled, cntp, w1, b1, w2, b2, out);
}

// Round 9
// 143.836 us; speedup vs baseline: 4.7238x; 1.0441x over previous
//
#include <hip/hip_runtime.h>

#define NN 50000
#define NE 800000
#define NG 64
#define HID 64
#define NEG 0.2f
#define NPW 64          // nodes per wave in k_node
#define NBUCK 196       // ceil(NN/256) coarse buckets (dst>>8)
#define CHUNK 2048      // edges per k_bucket block
#define KC_CAP 6144     // per-bucket ebuf segment (mean 4096 + 32 sigma)

// ---------------- K1: h = x @ W ; a_s = h.att_src ; a_d = h.att_dst --------
// Register-tiled f32 GEMM: block = 16x16 threads, 64-row tile, 4x4 micro-tile.
// Block 0 also zeroes gcur for the downstream k_bucket (runs after k_xw).
__global__ __launch_bounds__(256)
void k_xw(const float* __restrict__ x, const float* __restrict__ W,
          const float* __restrict__ att_s, const float* __restrict__ att_d,
          float* __restrict__ h, float* __restrict__ as_, float* __restrict__ ad_,
          int* __restrict__ gcur) {
    __shared__ __align__(16) float sW[64][64];    // [k][c]
    __shared__ __align__(16) float sxT[64][68];   // [k][r]
    int t = threadIdx.x;
    if (blockIdx.x == 0 && t < NBUCK) gcur[t] = 0;   // replaces hipMemsetAsync
    int r0 = blockIdx.x * 64;
    for (int i = t; i < 4096; i += 256) sW[i >> 6][i & 63] = W[i];
    for (int i = t; i < 4096; i += 256) {
        int r = i >> 6, c = i & 63;
        int gr = r0 + r; if (gr >= NN) gr = NN - 1;
        sxT[c][r] = x[(size_t)gr * 64 + c];
    }
    __syncthreads();

    int tx = t & 15, ty = t >> 4;
    float4 asv = ((const float4*)att_s)[tx];
    float4 adv = ((const float4*)att_d)[tx];

    float acc[4][4] = {};
    #pragma unroll
    for (int k = 0; k < 64; ++k) {
        float4 a = *(const float4*)&sxT[k][4 * ty];
        float4 b = *(const float4*)&sW[k][4 * tx];
        float av[4] = {a.x, a.y, a.z, a.w};
        float bv[4] = {b.x, b.y, b.z, b.w};
        #pragma unroll
        for (int i = 0; i < 4; ++i)
            #pragma unroll
            for (int j = 0; j < 4; ++j)
                acc[i][j] += av[i] * bv[j];
    }

    #pragma unroll
    for (int i = 0; i < 4; ++i) {
        int r = r0 + 4 * ty + i;
        if (r < NN) {
            float4 hv = make_float4(acc[i][0], acc[i][1], acc[i][2], acc[i][3]);
            *(float4*)&h[(size_t)r * 64 + 4 * tx] = hv;
            float ps = acc[i][0]*asv.x + acc[i][1]*asv.y + acc[i][2]*asv.z + acc[i][3]*asv.w;
            float pd = acc[i][0]*adv.x + acc[i][1]*adv.y + acc[i][2]*adv.z + acc[i][3]*adv.w;
            #pragma unroll
            for (int m = 1; m <= 8; m <<= 1) {
                ps += __shfl_xor(ps, m, 64);
                pd += __shfl_xor(pd, m, 64);
            }
            if (tx == 0) { as_[r] = ps; ad_[r] = pd; }
        }
    }
}

// ---------------- Pass B: blockwise bucket sort (dst>>8) ------------------
// Bucket b owns ebuf[b*KC_CAP ..]; blocks reserve sub-segments via gcur[b].
__global__ __launch_bounds__(256)
void k_bucket(const int* __restrict__ src, const int* __restrict__ dst,
              int* __restrict__ gcur, int* __restrict__ ebuf) {
    __shared__ int lhist[256], lscan[256], loff[256], lcur[256], gbase[256];
    __shared__ int lsort[CHUNK];
    __shared__ unsigned char lbuck[CHUNK];
    int t = threadIdx.x;
    int base = blockIdx.x * CHUNK;
    int cnt = NE - base; if (cnt > CHUNK) cnt = CHUNK; if (cnt < 0) cnt = 0;

    int ds[8], ss[8];
    int nv = 0;
    #pragma unroll
    for (int j = 0; j < 8; ++j) {
        int e = base + j * 256 + t;
        if (e < NE) { ds[nv] = dst[e]; ss[nv] = src[e]; ++nv; }
    }
    lhist[t] = 0;
    __syncthreads();
    for (int j = 0; j < nv; ++j) atomicAdd(&lhist[ds[j] >> 8], 1);
    __syncthreads();
    lscan[t] = lhist[t];
    __syncthreads();
    for (int off = 1; off < 256; off <<= 1) {
        int u = (t >= off) ? lscan[t - off] : 0;
        __syncthreads();
        lscan[t] += u;
        __syncthreads();
    }
    loff[t] = lscan[t] - lhist[t];   // exclusive
    lcur[t] = 0;
    __syncthreads();
    for (int j = 0; j < nv; ++j) {
        int b = ds[j] >> 8;
        int r = atomicAdd(&lcur[b], 1);
        int slot = loff[b] + r;
        lsort[slot] = (ss[j] << 8) | (ds[j] & 255);   // src<50000 fits in 24b
        lbuck[slot] = (unsigned char)b;
    }
    if (t < NBUCK) {
        int c = lhist[t];
        gbase[t] = c ? atomicAdd(&gcur[t], c) : 0;    // offset WITHIN bucket t
    }
    __syncthreads();
    for (int i = t; i < cnt; i += 256) {
        int b = lbuck[i];
        ebuf[b * KC_CAP + gbase[b] + (i - loff[b])] = lsort[i];
    }
}

// ---------------- Pass C: exact CSR within each bucket --------------------
__global__ __launch_bounds__(256)
void k_csr(const int* __restrict__ gcur, const int* __restrict__ ebuf,
           int* __restrict__ csr, int* __restrict__ cursor, int* __restrict__ deg) {
    __shared__ int lhist[256], lscan[256], loff[256], lcur[256], bscan[256];
    __shared__ int lsrc[KC_CAP];
    int t = threadIdx.x;
    int b = blockIdx.x;

    bscan[t] = (t < NBUCK) ? gcur[t] : 0;     // bucket sizes
    __syncthreads();
    for (int off = 1; off < 256; off <<= 1) {
        int u = (t >= off) ? bscan[t - off] : 0;
        __syncthreads();
        bscan[t] += u;
        __syncthreads();
    }
    int sz = gcur[b];                          // this bucket's edge count
    int gb = bscan[b] - sz;                    // dense CSR base (exclusive)
    const int* seg = ebuf + b * KC_CAP;

    lhist[t] = 0;
    __syncthreads();
    for (int i = t; i < sz; i += 256)
        atomicAdd(&lhist[seg[i] & 255], 1);
    __syncthreads();
    lscan[t] = lhist[t];
    __syncthreads();
    for (int off = 1; off < 256; off <<= 1) {
        int u = (t >= off) ? lscan[t - off] : 0;
        __syncthreads();
        lscan[t] += u;
        __syncthreads();
    }
    loff[t] = lscan[t] - lhist[t];
    lcur[t] = 0;
    __syncthreads();
    for (int i = t; i < sz; i += 256) {
        int w = seg[i];
        int dl = w & 255;
        int r = atomicAdd(&lcur[dl], 1);
        lsrc[loff[dl] + r] = w >> 8;
    }
    __syncthreads();
    for (int i = t; i < sz; i += 256)
        csr[gb + i] = lsrc[i];
    int d = b * 256 + t;
    if (d < NN) {
        deg[d] = lhist[t];
        cursor[d] = gb + loff[t] + lhist[t];   // end offset
    }
}

// ---------------- K2': gather per dst node (no atomics) -------------------
// Block 0 also zeroes pooled+cnt for the downstream k_node (runs after).
__global__ __launch_bounds__(256)
void k_gather(const int* __restrict__ csr, const int* __restrict__ cursor,
              const int* __restrict__ deg, const float* __restrict__ h,
              const float* __restrict__ as_, const float* __restrict__ ad_,
              const float* __restrict__ bias, float* __restrict__ g,
              float* __restrict__ poolz) {
    int t = threadIdx.x;
    if (blockIdx.x == 0) {                        // replaces hipMemsetAsync
        for (int i = t; i < NG * HID + NG; i += 256) poolz[i] = 0.f;
    }
    int wave = t >> 6, lane = t & 63;
    int d = blockIdx.x * 4 + wave;
    if (d >= NN) return;
    int cend = cursor[d];
    int nd   = deg[d];
    int cbeg = cend - nd;
    float adv = ad_[d];
    float e0 = as_[d] + adv;
    e0 = e0 >= 0.f ? e0 : NEG * e0;
    float ex0 = __expf(e0);
    float den = ex0;
    float acc = h[(size_t)d * 64 + lane] * ex0;
    #pragma unroll 4
    for (int c = cbeg; c < cend; ++c) {
        int s = csr[c];
        float av = as_[s] + adv;
        av = av >= 0.f ? av : NEG * av;
        float ex = __expf(av);
        den += ex;
        acc += h[(size_t)s * 64 + lane] * ex;
    }
    g[(size_t)d * 64 + lane] = fmaxf(acc / den + bias[lane], 0.f);
}

// ---------------- K3: pooled partial sums (batch sorted, run-length) ------
__global__ __launch_bounds__(256)
void k_node(const float* __restrict__ g, const int* __restrict__ batch,
            float* __restrict__ pooled, float* __restrict__ cnt) {
    int t = threadIdx.x;
    int wave = t >> 6, lane = t & 63;
    int n0 = (blockIdx.x * 4 + wave) * NPW;
    if (n0 >= NN) return;
    int n1 = n0 + NPW; if (n1 > NN) n1 = NN;
    float acc = 0.f, c = 0.f;
    int cur = batch[n0];
    for (int n = n0; n < n1; ++n) {
        int gr = batch[n];
        if (gr != cur) {
            atomicAdd(&pooled[cur * 64 + lane], acc);
            if (lane == 0) atomicAdd(&cnt[cur], c);
            acc = 0.f; c = 0.f; cur = gr;
        }
        acc += g[(size_t)n * 64 + lane];
        c += 1.f;
    }
    atomicAdd(&pooled[cur * 64 + lane], acc);
    if (lane == 0) atomicAdd(&cnt[cur], c);
}

// ---------------- K4: mean + MLP + sigmoid (single block) ------------------
__global__ __launch_bounds__(256)
void k_final(const float* __restrict__ pooled, const float* __restrict__ cnt,
             const float* __restrict__ w1, const float* __restrict__ b1,
             const float* __restrict__ w2, const float* __restrict__ b2,
             float* __restrict__ out) {
    __shared__ float sp[64][65];
    __shared__ float sz[64][65];
    int t = threadIdx.x;
    for (int i = t; i < 4096; i += 256) {
        int g = i >> 6, c = i & 63;
        sp[g][c] = pooled[i] / fmaxf(cnt[g], 1.0f);
    }
    __syncthreads();
    for (int i = t; i < 4096; i += 256) {
        int g = i >> 6, c = i & 63;
        float acc = b1[c];
        #pragma unroll
        for (int k = 0; k < 64; ++k) acc += sp[g][k] * w1[k * 64 + c];
        sz[g][c] = fmaxf(acc, 0.f);
    }
    __syncthreads();
    if (t < 64) {
        float acc = b2[0];
        #pragma unroll
        for (int c = 0; c < 64; ++c) acc += sz[t][c] * w2[c];
        out[t] = 1.f / (1.f + __expf(-acc));
    }
}

extern "C" void kernel_launch(void* const* d_in, const int* in_sizes, int n_in,
                              void* d_out, int out_size, void* d_ws, size_t ws_size,
                              hipStream_t stream) {
    const float* x     = (const float*)d_in[0];
    const int*   ei    = (const int*)d_in[1];   // [2, NE] flat: src row then dst row
    const int*   batch = (const int*)d_in[2];
    const float* W     = (const float*)d_in[3];
    const float* att_s = (const float*)d_in[4];
    const float* att_d = (const float*)d_in[5];
    const float* bias  = (const float*)d_in[6];
    const float* w1    = (const float*)d_in[7];
    const float* b1    = (const float*)d_in[8];
    const float* w2    = (const float*)d_in[9];
    const float* b2    = (const float*)d_in[10];
    float* out = (float*)d_out;

    const int* src = ei;
    const int* dst = ei + NE;

    // workspace layout (floats / ints)
    float* h      = (float*)d_ws;               // NN*64
    float* as_    = h + (size_t)NN * HID;       // NN
    float* ad_    = as_ + NN;                   // NN
    float* g      = ad_ + NN;                   // NN*64  (ebuf aliases this)
    float* pooled = g + (size_t)NN * HID;       // NG*64
    float* cntp   = pooled + NG * HID;          // NG
    int*   deg    = (int*)(cntp + NG);          // NN
    int*   cursor = deg + NN;                   // NN
    int*   csr    = cursor + NN;                // NE
    int*   gcur   = csr + NE;                   // NBUCK
    int*   ebuf   = (int*)g;                    // NBUCK*KC_CAP (= 4.6MB < NN*64*4)
                                                // lifetime: k_bucket..k_csr only

    // no hipMemsetAsync: gcur zeroed in k_xw, pooled+cnt zeroed in k_gather

    k_xw<<<(NN + 63) / 64, 256, 0, stream>>>(x, W, att_s, att_d, h, as_, ad_, gcur);

    k_bucket<<<(NE + CHUNK - 1) / CHUNK, 256, 0, stream>>>(src, dst, gcur, ebuf);
    k_csr<<<NBUCK, 256, 0, stream>>>(gcur, ebuf, csr, cursor, deg);

    k_gather<<<(NN + 3) / 4, 256, 0, stream>>>(csr, cursor, deg, h, as_, ad_, bias, g, pooled);

    k_node<<<(NN / (4 * NPW)) + 1, 256, 0, stream>>>(g, batch, pooled, cntp);

    k_final<<<1, 256, 0, stream>>>(pooled, cntp, w1, b1, w2, b2, out);
}